// Round 1
// baseline (4582.327 us; speedup 1.0000x reference)
//
#include <hip/hip_runtime.h>

typedef unsigned int u32;
typedef unsigned short us16;
typedef __bf16 bf16x8 __attribute__((ext_vector_type(8)));
typedef float f32x4 __attribute__((ext_vector_type(4)));

// ---------- constants ----------
constexpr int S    = 2304;   // tokens per stream
constexpr int D    = 2048;
constexpr int NH   = 16;
constexpr int HD   = 128;
constexpr int FFN  = 8192;
constexpr int F4   = 4;      // frames
constexpr int CT   = 1152;   // combined tokens per frame (24 * 48)
constexpr float ATTN_SCALE = 0.08838834764831845f; // 128^-0.5

// ---------- helpers ----------
__device__ __forceinline__ float bflo(u32 r) { return __uint_as_float(r << 16); }
__device__ __forceinline__ float bfhi(u32 r) { return __uint_as_float(r & 0xffff0000u); }
__device__ __forceinline__ us16 f2bf(float f) {
  u32 x = __float_as_uint(f);
  x += 0x7fffu + ((x >> 16) & 1u);   // RNE
  return (us16)(x >> 16);
}
__device__ __forceinline__ float blk_sum256(float v, float* red, int tid) {
  #pragma unroll
  for (int o = 32; o; o >>= 1) v += __shfl_down(v, o, 64);
  __syncthreads();
  if ((tid & 63) == 0) red[tid >> 6] = v;
  __syncthreads();
  return red[0] + red[1] + red[2] + red[3];
}

// ---------- fp32 (KxN) -> bf16 transposed (NxK) ----------
__global__ __launch_bounds__(256) void transpose_cvt(
    const float* __restrict__ in, us16* __restrict__ out, int Kd, int Nd) {
  __shared__ float tile[32][33];
  int tx = threadIdx.x, ty = threadIdx.y;
  int n0 = blockIdx.x * 32, k0 = blockIdx.y * 32;
  #pragma unroll
  for (int i = 0; i < 4; i++)
    tile[ty + i * 8][tx] = in[(size_t)(k0 + ty + i * 8) * Nd + n0 + tx];
  __syncthreads();
  #pragma unroll
  for (int i = 0; i < 4; i++)
    out[(size_t)(n0 + ty + i * 8) * Kd + k0 + tx] = f2bf(tile[tx][ty + i * 8]);
}

// ---------- t = silu(temb) @ lw + lb  (two sets: ln1, ln2) ----------
__global__ __launch_bounds__(256) void temb_mod(
    const float* __restrict__ temb,
    const float* __restrict__ lw1, const float* __restrict__ lb1,
    const float* __restrict__ lw2, const float* __restrict__ lb2,
    float* __restrict__ t1, float* __restrict__ t2) {
  __shared__ float st[512];
  int tid = threadIdx.x;
  for (int i = tid; i < 512; i += 256) {
    float v = temb[i];
    st[i] = v / (1.0f + __expf(-v));
  }
  __syncthreads();
  int which = blockIdx.x / 24;
  int n = (blockIdx.x % 24) * 256 + tid;
  const float* lw = which ? lw2 : lw1;
  const float* lb = which ? lb2 : lb1;
  float acc = lb[n];
  #pragma unroll 4
  for (int k = 0; k < 512; k++) acc += st[k] * lw[(size_t)k * (3 * D) + n];
  (which ? t2 : t1)[n] = acc;
}

// ---------- layernorm + adaLN modulate -> bf16 ----------
__global__ __launch_bounds__(256) void ln_mod(
    const float* __restrict__ x, const float* __restrict__ t,
    const float* __restrict__ nw, const float* __restrict__ nb,
    us16* __restrict__ out) {
  __shared__ float red[4];
  int tok = blockIdx.x, tid = threadIdx.x;
  const float* xr = x + (size_t)tok * D;
  float v[8];
  float4 a = *(const float4*)(xr + tid * 8);
  float4 b = *(const float4*)(xr + tid * 8 + 4);
  v[0]=a.x; v[1]=a.y; v[2]=a.z; v[3]=a.w; v[4]=b.x; v[5]=b.y; v[6]=b.z; v[7]=b.w;
  float s = 0;
  #pragma unroll
  for (int i = 0; i < 8; i++) s += v[i];
  float mu = blk_sum256(s, red, tid) * (1.0f / D);
  float sq = 0;
  #pragma unroll
  for (int i = 0; i < 8; i++) { float d = v[i] - mu; sq += d * d; }
  float var = blk_sum256(sq, red, tid) * (1.0f / D);
  float rinv = rsqrtf(var + 1e-5f);
  int n = tid * 8;
  us16 o[8];
  #pragma unroll
  for (int i = 0; i < 8; i++) {
    float xn = (v[i] - mu) * rinv * nw[n + i] + nb[n + i];
    float y = xn * (1.0f + t[D + n + i]) + t[n + i];
    o[i] = f2bf(y);
  }
  *(uint4*)(out + (size_t)tok * D + n) = *(uint4*)o;
}

// ---------- GEMM: C(MxN,f32) = A(MxK,bf16) @ BT(NxK,bf16)^T + bias ----------
__global__ __launch_bounds__(256) void gemm_bf16(
    const us16* __restrict__ A, const us16* __restrict__ BT,
    const float* __restrict__ bias, float* __restrict__ C,
    int M, int N, int K) {
  __shared__ __align__(16) us16 As[64][40];
  __shared__ __align__(16) us16 Bs[64][40];
  int tid = threadIdx.x;
  int w = tid >> 6, l = tid & 63;
  int m0 = blockIdx.y << 6, n0 = blockIdx.x << 6;
  int lrow = tid >> 2, lk = (tid & 3) << 3;
  const us16* Ap = A + (size_t)(m0 + lrow) * K + lk;
  const us16* Bp = BT + (size_t)(n0 + lrow) * K + lk;
  int arow = (w << 4) + (l & 15);
  int koff = (l >> 4) << 3;
  int ncol = l & 15;
  f32x4 acc[4] = {};
  for (int k0 = 0; k0 < K; k0 += 32) {
    uint4 av = *(const uint4*)(Ap + k0);
    uint4 bv = *(const uint4*)(Bp + k0);
    __syncthreads();
    *(uint4*)&As[lrow][lk] = av;
    *(uint4*)&Bs[lrow][lk] = bv;
    __syncthreads();
    bf16x8 af = *(const bf16x8*)&As[arow][koff];
    bf16x8 b0 = *(const bf16x8*)&Bs[ncol][koff];
    bf16x8 b1 = *(const bf16x8*)&Bs[16 + ncol][koff];
    bf16x8 b2 = *(const bf16x8*)&Bs[32 + ncol][koff];
    bf16x8 b3 = *(const bf16x8*)&Bs[48 + ncol][koff];
    acc[0] = __builtin_amdgcn_mfma_f32_16x16x32_bf16(af, b0, acc[0], 0, 0, 0);
    acc[1] = __builtin_amdgcn_mfma_f32_16x16x32_bf16(af, b1, acc[1], 0, 0, 0);
    acc[2] = __builtin_amdgcn_mfma_f32_16x16x32_bf16(af, b2, acc[2], 0, 0, 0);
    acc[3] = __builtin_amdgcn_mfma_f32_16x16x32_bf16(af, b3, acc[3], 0, 0, 0);
  }
  int r0 = m0 + (w << 4) + ((l >> 4) << 2);
  #pragma unroll
  for (int nt = 0; nt < 4; nt++) {
    int col = n0 + nt * 16 + ncol;
    float bv = bias ? bias[col] : 0.0f;
    #pragma unroll
    for (int r = 0; r < 4; r++)
      C[(size_t)(r0 + r) * N + col] = acc[nt][r] + bv;
  }
}

// ---------- QK rmsnorm + rope + combine-scatter (mode 0=q,1=k,2=v) ----------
__global__ __launch_bounds__(256) void qkv_scatter(
    const float* __restrict__ in, const float* __restrict__ nw,
    const float* __restrict__ cosv, const float* __restrict__ sinv,
    us16* __restrict__ out, int mode, int is_ref) {
  __shared__ float red[4];
  int t = blockIdx.x, tid = threadIdx.x;
  const float* xr = in + (size_t)t * D;
  float v[8];
  float4 a = *(const float4*)(xr + tid * 8);
  float4 b = *(const float4*)(xr + tid * 8 + 4);
  v[0]=a.x; v[1]=a.y; v[2]=a.z; v[3]=a.w; v[4]=b.x; v[5]=b.y; v[6]=b.z; v[7]=b.w;
  int n = tid * 8;
  int head = n >> 7, d = n & 127;
  float o8[8];
  if (mode < 2) {
    float s = 0;
    #pragma unroll
    for (int i = 0; i < 8; i++) s += v[i] * v[i];
    float tot = blk_sum256(s, red, tid);
    float rinv = rsqrtf(tot * (1.0f / D) + 1e-6f);
    const float* cr = cosv + (size_t)t * HD;
    const float* sr = sinv + (size_t)t * HD;
    #pragma unroll
    for (int p = 0; p < 4; p++) {
      float x1 = v[2 * p] * rinv * nw[n + 2 * p];
      float x2 = v[2 * p + 1] * rinv * nw[n + 2 * p + 1];
      float ce = cr[d + 2 * p];
      float so = sr[d + 2 * p + 1];
      o8[2 * p]     = x1 * ce - x2 * so;
      o8[2 * p + 1] = x1 * so + x2 * ce;
    }
    if (mode == 0) {
      #pragma unroll
      for (int i = 0; i < 8; i++) o8[i] *= ATTN_SCALE;
    }
  } else {
    #pragma unroll
    for (int i = 0; i < 8; i++) o8[i] = v[i];
  }
  int f = t / 576, rem = t % 576;
  int row = rem / 24, col = rem - row * 24;
  int comb = row * 48 + col + (is_ref ? 24 : 0);
  size_t oidx = ((size_t)(f * NH + head) * CT + comb) * HD + d;
  us16 packed[8];
  #pragma unroll
  for (int i = 0; i < 8; i++) packed[i] = f2bf(o8[i]);
  *(uint4*)(out + oidx) = *(uint4*)packed;
}

// ---------- naive attention: 1 wave per query ----------
__global__ __launch_bounds__(256) void attn_naive(
    const us16* __restrict__ qc, const us16* __restrict__ kc,
    const us16* __restrict__ vc, us16* __restrict__ ah, us16* __restrict__ ar) {
  __shared__ float lg[4][CT];
  __shared__ float qvs[4][HD];
  int tid = threadIdx.x, w = tid >> 6, l = tid & 63;
  int bx = blockIdx.x;
  int fh = bx / 288;              // frame*16 + head
  int qi = (bx % 288) * 4 + w;    // combined query index
  size_t base = (size_t)fh * CT * HD;
  u32 qraw = *(const u32*)(qc + base + (size_t)qi * HD + 2 * l);
  qvs[w][2 * l] = bflo(qraw);
  qvs[w][2 * l + 1] = bfhi(qraw);
  __syncthreads();
  float m = -1e30f;
  for (int j = l; j < CT; j += 64) {
    const uint4* kr = (const uint4*)(kc + base + (size_t)j * HD);
    float s = 0.f;
    #pragma unroll
    for (int c = 0; c < 16; c++) {
      uint4 r = kr[c];
      const float* qp = &qvs[w][c * 8];
      s += bflo(r.x) * qp[0] + bfhi(r.x) * qp[1];
      s += bflo(r.y) * qp[2] + bfhi(r.y) * qp[3];
      s += bflo(r.z) * qp[4] + bfhi(r.z) * qp[5];
      s += bflo(r.w) * qp[6] + bfhi(r.w) * qp[7];
    }
    lg[w][j] = s;
    m = fmaxf(m, s);
  }
  #pragma unroll
  for (int o = 32; o; o >>= 1) m = fmaxf(m, __shfl_xor(m, o, 64));
  float ps = 0.f;
  for (int j = l; j < CT; j += 64) {
    float p = __expf(lg[w][j] - m);
    lg[w][j] = p;
    ps += p;
  }
  #pragma unroll
  for (int o = 32; o; o >>= 1) ps += __shfl_xor(ps, o, 64);
  float rl = 1.0f / ps;
  __syncthreads();
  float a0 = 0.f, a1 = 0.f;
  const us16* vb = vc + base + 2 * l;
  for (int j4 = 0; j4 < CT; j4 += 4) {
    float4 p4 = *(const float4*)&lg[w][j4];
    u32 r0 = *(const u32*)(vb + (size_t)(j4 + 0) * HD);
    u32 r1 = *(const u32*)(vb + (size_t)(j4 + 1) * HD);
    u32 r2 = *(const u32*)(vb + (size_t)(j4 + 2) * HD);
    u32 r3 = *(const u32*)(vb + (size_t)(j4 + 3) * HD);
    a0 += p4.x * bflo(r0) + p4.y * bflo(r1) + p4.z * bflo(r2) + p4.w * bflo(r3);
    a1 += p4.x * bfhi(r0) + p4.y * bfhi(r1) + p4.z * bfhi(r2) + p4.w * bfhi(r3);
  }
  a0 *= rl; a1 *= rl;
  int f = fh >> 4, h = fh & 15;
  int row = qi / 48, col = qi - row * 48;
  int isr = col >= 24;
  int tok = f * 576 + row * 24 + (isr ? col - 24 : col);
  us16* dst = (isr ? ar : ah) + (size_t)tok * D + h * HD + 2 * l;
  u32 packed = (u32)f2bf(a0) | ((u32)f2bf(a1) << 16);
  *(u32*)dst = packed;
}

// ---------- out = x + gate[col] * attn ----------
__global__ __launch_bounds__(256) void residual_gate(
    const float* __restrict__ x, const float* __restrict__ attn,
    const float* __restrict__ gate, float* __restrict__ out) {
  size_t i = ((size_t)blockIdx.x * 256 + threadIdx.x) * 4;
  float4 xv = *(const float4*)(x + i);
  float4 av = *(const float4*)(attn + i);
  int n = (int)(i & (D - 1));
  float4 g = *(const float4*)(gate + n);
  float4 o;
  o.x = xv.x + g.x * av.x;
  o.y = xv.y + g.y * av.y;
  o.z = xv.z + g.z * av.z;
  o.w = xv.w + g.w * av.w;
  *(float4*)(out + i) = o;
}

// ---------- gelu(tanh) fp32 -> bf16 ----------
__device__ __forceinline__ float gelu_tanh(float x) {
  float y = 0.7978845608028654f * (x + 0.044715f * x * x * x);
  float e = __expf(2.0f * y);
  float t = 1.0f - 2.0f / (e + 1.0f);
  return 0.5f * x * (1.0f + t);
}
__global__ __launch_bounds__(256) void gelu_cvt(
    const float* __restrict__ in, us16* __restrict__ out, int n4) {
  int i = blockIdx.x * 256 + threadIdx.x;
  if (i >= n4) return;
  float4 v = *(const float4*)(in + (size_t)i * 4);
  us16 o[4];
  o[0] = f2bf(gelu_tanh(v.x));
  o[1] = f2bf(gelu_tanh(v.y));
  o[2] = f2bf(gelu_tanh(v.z));
  o[3] = f2bf(gelu_tanh(v.w));
  *(uint2*)(out + (size_t)i * 4) = *(uint2*)o;
}

// ---------- workspace layout (bytes) ----------
// attention phase:
constexpr size_t O_WQ   = 0;
constexpr size_t O_WK   = 8388608;
constexpr size_t O_WV   = 16777216;
constexpr size_t O_WO   = 25165824;
constexpr size_t O_NH   = 33603584;   // bf16 S*D
constexpr size_t O_NR   = 43040768;
constexpr size_t O_RAW  = 52477952;   // 6 x fp32 S*D (18,874,368 B each)
constexpr size_t RAWSZ  = 18874368;
constexpr size_t O_QC   = 165724160;  // bf16 combined
constexpr size_t O_KC   = 184598528;
constexpr size_t O_VC   = 203472896;
constexpr size_t O_T1   = 222347264;  // fp32 6144
constexpr size_t O_T2   = 222371840;
// reuse of O_RAW after scatter:
constexpr size_t O_AH    = O_RAW;                 // bf16 S*D
constexpr size_t O_AR    = O_RAW + 9437184;       // bf16 S*D
constexpr size_t O_ATTNH = O_RAW + RAWSZ;         // fp32 S*D
constexpr size_t O_ATTNR = O_RAW + 2 * RAWSZ;     // fp32 S*D
// FFN phase (weights region + raw region are dead):
constexpr size_t O_W1T  = 0;          // bf16 FFN*D transposed
constexpr size_t O_W2T  = 33554432;   // bf16 D*FFN transposed
constexpr size_t O_N2H  = 67108864;   // bf16 S*D
constexpr size_t O_N2R  = 76546048;
constexpr size_t O_MID  = 85983232;   // fp32 S*FFN
constexpr size_t O_MIDB = 161480704;  // bf16 S*FFN
constexpr size_t O_FOUT = 199229440;  // fp32 S*D
// total needed: 222,396,416 bytes (~212 MiB)

extern "C" void kernel_launch(void* const* d_in, const int* in_sizes, int n_in,
                              void* d_out, int out_size, void* d_ws, size_t ws_size,
                              hipStream_t stream) {
  (void)in_sizes; (void)n_in; (void)out_size; (void)ws_size;
  const float* hidden = (const float*)d_in[0];
  const float* refs   = (const float*)d_in[1];
  const float* temb   = (const float*)d_in[2];
  const float* cos_h  = (const float*)d_in[3];
  const float* sin_h  = (const float*)d_in[4];
  const float* cos_r  = (const float*)d_in[5];
  const float* sin_r  = (const float*)d_in[6];
  const float* ln1_lw = (const float*)d_in[7];
  const float* ln1_lb = (const float*)d_in[8];
  const float* ln1_nw = (const float*)d_in[9];
  const float* ln1_nb = (const float*)d_in[10];
  const float* ln2_lw = (const float*)d_in[11];
  const float* ln2_lb = (const float*)d_in[12];
  const float* ln2_nw = (const float*)d_in[13];
  const float* ln2_nb = (const float*)d_in[14];
  const float* wq = (const float*)d_in[15];
  const float* bq = (const float*)d_in[16];
  const float* wk = (const float*)d_in[17];
  const float* bk = (const float*)d_in[18];
  const float* wv = (const float*)d_in[19];
  const float* bv = (const float*)d_in[20];
  const float* nq_w = (const float*)d_in[21];
  const float* nk_w = (const float*)d_in[22];
  const float* wo = (const float*)d_in[23];
  const float* bo = (const float*)d_in[24];
  const float* ffn_w1 = (const float*)d_in[25];
  const float* ffn_b1 = (const float*)d_in[26];
  const float* ffn_w2 = (const float*)d_in[27];
  const float* ffn_b2 = (const float*)d_in[28];

  char* ws = (char*)d_ws;
  us16* p_wq = (us16*)(ws + O_WQ);
  us16* p_wk = (us16*)(ws + O_WK);
  us16* p_wv = (us16*)(ws + O_WV);
  us16* p_wo = (us16*)(ws + O_WO);
  us16* p_nh = (us16*)(ws + O_NH);
  us16* p_nr = (us16*)(ws + O_NR);
  float* p_raw[6];
  for (int i = 0; i < 6; i++) p_raw[i] = (float*)(ws + O_RAW + (size_t)i * RAWSZ);
  us16* p_qc = (us16*)(ws + O_QC);
  us16* p_kc = (us16*)(ws + O_KC);
  us16* p_vc = (us16*)(ws + O_VC);
  float* p_t1 = (float*)(ws + O_T1);
  float* p_t2 = (float*)(ws + O_T2);
  us16* p_ah = (us16*)(ws + O_AH);
  us16* p_ar = (us16*)(ws + O_AR);
  float* p_attnh = (float*)(ws + O_ATTNH);
  float* p_attnr = (float*)(ws + O_ATTNR);
  us16* p_w1t = (us16*)(ws + O_W1T);
  us16* p_w2t = (us16*)(ws + O_W2T);
  us16* p_n2h = (us16*)(ws + O_N2H);
  us16* p_n2r = (us16*)(ws + O_N2R);
  float* p_mid  = (float*)(ws + O_MID);
  us16*  p_midb = (us16*)(ws + O_MIDB);
  float* p_fout = (float*)(ws + O_FOUT);
  float* outh = (float*)d_out;
  float* outr = (float*)d_out + (size_t)S * D;

  dim3 tb(32, 8);
  // attention-phase weights
  transpose_cvt<<<dim3(64, 64), tb, 0, stream>>>(wq, p_wq, D, D);
  transpose_cvt<<<dim3(64, 64), tb, 0, stream>>>(wk, p_wk, D, D);
  transpose_cvt<<<dim3(64, 64), tb, 0, stream>>>(wv, p_wv, D, D);
  transpose_cvt<<<dim3(64, 64), tb, 0, stream>>>(wo, p_wo, D, D);
  // adaLN tables
  temb_mod<<<48, 256, 0, stream>>>(temb, ln1_lw, ln1_lb, ln2_lw, ln2_lb, p_t1, p_t2);
  // LN1 + modulate
  ln_mod<<<S, 256, 0, stream>>>(hidden, p_t1, ln1_nw, ln1_nb, p_nh);
  ln_mod<<<S, 256, 0, stream>>>(refs,   p_t1, ln1_nw, ln1_nb, p_nr);
  // QKV GEMMs
  gemm_bf16<<<dim3(32, 36), 256, 0, stream>>>(p_nh, p_wq, bq, p_raw[0], S, D, D);
  gemm_bf16<<<dim3(32, 36), 256, 0, stream>>>(p_nh, p_wk, bk, p_raw[1], S, D, D);
  gemm_bf16<<<dim3(32, 36), 256, 0, stream>>>(p_nh, p_wv, bv, p_raw[2], S, D, D);
  gemm_bf16<<<dim3(32, 36), 256, 0, stream>>>(p_nr, p_wq, bq, p_raw[3], S, D, D);
  gemm_bf16<<<dim3(32, 36), 256, 0, stream>>>(p_nr, p_wk, bk, p_raw[4], S, D, D);
  gemm_bf16<<<dim3(32, 36), 256, 0, stream>>>(p_nr, p_wv, bv, p_raw[5], S, D, D);
  // rmsnorm + rope + combine
  qkv_scatter<<<S, 256, 0, stream>>>(p_raw[0], nq_w, cos_h, sin_h, p_qc, 0, 0);
  qkv_scatter<<<S, 256, 0, stream>>>(p_raw[1], nk_w, cos_h, sin_h, p_kc, 1, 0);
  qkv_scatter<<<S, 256, 0, stream>>>(p_raw[2], nq_w, cos_h, sin_h, p_vc, 2, 0);
  qkv_scatter<<<S, 256, 0, stream>>>(p_raw[3], nq_w, cos_r, sin_r, p_qc, 0, 1);
  qkv_scatter<<<S, 256, 0, stream>>>(p_raw[4], nk_w, cos_r, sin_r, p_kc, 1, 1);
  qkv_scatter<<<S, 256, 0, stream>>>(p_raw[5], nq_w, cos_r, sin_r, p_vc, 2, 1);
  // attention
  attn_naive<<<F4 * NH * (CT / 4), 256, 0, stream>>>(p_qc, p_kc, p_vc, p_ah, p_ar);
  // O-proj
  gemm_bf16<<<dim3(32, 36), 256, 0, stream>>>(p_ah, p_wo, bo, p_attnh, S, D, D);
  gemm_bf16<<<dim3(32, 36), 256, 0, stream>>>(p_ar, p_wo, bo, p_attnr, S, D, D);
  // residual with gate1
  residual_gate<<<4608, 256, 0, stream>>>(hidden, p_attnh, p_t1 + 2 * D, outh);
  residual_gate<<<4608, 256, 0, stream>>>(refs,   p_attnr, p_t1 + 2 * D, outr);
  // FFN-phase weights (reuse attention weight region)
  transpose_cvt<<<dim3(256, 64), tb, 0, stream>>>(ffn_w1, p_w1t, D, FFN);
  transpose_cvt<<<dim3(64, 256), tb, 0, stream>>>(ffn_w2, p_w2t, FFN, D);
  // LN2 + modulate
  ln_mod<<<S, 256, 0, stream>>>(outh, p_t2, ln2_nw, ln2_nb, p_n2h);
  ln_mod<<<S, 256, 0, stream>>>(outr, p_t2, ln2_nw, ln2_nb, p_n2r);
  // FFN hidden
  gemm_bf16<<<dim3(128, 36), 256, 0, stream>>>(p_n2h, p_w1t, ffn_b1, p_mid, S, FFN, D);
  gelu_cvt<<<18432, 256, 0, stream>>>(p_mid, p_midb, (S * FFN) / 4);
  gemm_bf16<<<dim3(32, 36), 256, 0, stream>>>(p_midb, p_w2t, ffn_b2, p_fout, S, D, FFN);
  residual_gate<<<4608, 256, 0, stream>>>(outh, p_fout, p_t2 + 2 * D, outh);
  // FFN ref
  gemm_bf16<<<dim3(128, 36), 256, 0, stream>>>(p_n2r, p_w1t, ffn_b1, p_mid, S, FFN, D);
  gelu_cvt<<<18432, 256, 0, stream>>>(p_mid, p_midb, (S * FFN) / 4);
  gemm_bf16<<<dim3(32, 36), 256, 0, stream>>>(p_midb, p_w2t, ffn_b2, p_fout, S, D, FFN);
  residual_gate<<<4608, 256, 0, stream>>>(outr, p_fout, p_t2 + 2 * D, outr);
}

// Round 3
// 1890.019 us; speedup vs baseline: 2.4245x; 2.4245x over previous
//
#include <hip/hip_runtime.h>

typedef unsigned int u32;
typedef unsigned short us16;
typedef __bf16 bf16x8 __attribute__((ext_vector_type(8)));
typedef float f32x4 __attribute__((ext_vector_type(4)));

// ---------- constants ----------
constexpr int S    = 2304;   // tokens per stream
constexpr int D    = 2048;
constexpr int NH   = 16;
constexpr int HD   = 128;
constexpr int FFN  = 8192;
constexpr int F4   = 4;      // frames
constexpr int CT   = 1152;   // combined tokens per frame (24 * 48)
constexpr float ATTN_SCALE = 0.08838834764831845f; // 128^-0.5

// ---------- helpers ----------
__device__ __forceinline__ float bflo(u32 r) { return __uint_as_float(r << 16); }
__device__ __forceinline__ float bfhi(u32 r) { return __uint_as_float(r & 0xffff0000u); }
__device__ __forceinline__ us16 f2bf(float f) {
  u32 x = __float_as_uint(f);
  x += 0x7fffu + ((x >> 16) & 1u);   // RNE
  return (us16)(x >> 16);
}
__device__ __forceinline__ float blk_sum256(float v, float* red, int tid) {
  #pragma unroll
  for (int o = 32; o; o >>= 1) v += __shfl_down(v, o, 64);
  __syncthreads();
  if ((tid & 63) == 0) red[tid >> 6] = v;
  __syncthreads();
  return red[0] + red[1] + red[2] + red[3];
}

// ---------- fp32 (KxN) -> bf16 transposed (NxK) ----------
__global__ __launch_bounds__(256) void transpose_cvt(
    const float* __restrict__ in, us16* __restrict__ out, int Kd, int Nd) {
  __shared__ float tile[32][33];
  int tx = threadIdx.x, ty = threadIdx.y;
  int n0 = blockIdx.x * 32, k0 = blockIdx.y * 32;
  #pragma unroll
  for (int i = 0; i < 4; i++)
    tile[ty + i * 8][tx] = in[(size_t)(k0 + ty + i * 8) * Nd + n0 + tx];
  __syncthreads();
  #pragma unroll
  for (int i = 0; i < 4; i++)
    out[(size_t)(n0 + ty + i * 8) * Kd + k0 + tx] = f2bf(tile[tx][ty + i * 8]);
}

// ---------- t = silu(temb) @ lw + lb  (two sets: ln1, ln2) ----------
__global__ __launch_bounds__(256) void temb_mod(
    const float* __restrict__ temb,
    const float* __restrict__ lw1, const float* __restrict__ lb1,
    const float* __restrict__ lw2, const float* __restrict__ lb2,
    float* __restrict__ t1, float* __restrict__ t2) {
  __shared__ float st[512];
  int tid = threadIdx.x;
  for (int i = tid; i < 512; i += 256) {
    float v = temb[i];
    st[i] = v / (1.0f + __expf(-v));
  }
  __syncthreads();
  int which = blockIdx.x / 24;
  int n = (blockIdx.x % 24) * 256 + tid;
  const float* lw = which ? lw2 : lw1;
  const float* lb = which ? lb2 : lb1;
  float acc = lb[n];
  #pragma unroll 4
  for (int k = 0; k < 512; k++) acc += st[k] * lw[(size_t)k * (3 * D) + n];
  (which ? t2 : t1)[n] = acc;
}

// ---------- layernorm + adaLN modulate -> bf16 ----------
__global__ __launch_bounds__(256) void ln_mod(
    const float* __restrict__ x, const float* __restrict__ t,
    const float* __restrict__ nw, const float* __restrict__ nb,
    us16* __restrict__ out) {
  __shared__ float red[4];
  int tok = blockIdx.x, tid = threadIdx.x;
  const float* xr = x + (size_t)tok * D;
  float v[8];
  float4 a = *(const float4*)(xr + tid * 8);
  float4 b = *(const float4*)(xr + tid * 8 + 4);
  v[0]=a.x; v[1]=a.y; v[2]=a.z; v[3]=a.w; v[4]=b.x; v[5]=b.y; v[6]=b.z; v[7]=b.w;
  float s = 0;
  #pragma unroll
  for (int i = 0; i < 8; i++) s += v[i];
  float mu = blk_sum256(s, red, tid) * (1.0f / D);
  float sq = 0;
  #pragma unroll
  for (int i = 0; i < 8; i++) { float d = v[i] - mu; sq += d * d; }
  float var = blk_sum256(sq, red, tid) * (1.0f / D);
  float rinv = rsqrtf(var + 1e-5f);
  int n = tid * 8;
  us16 o[8];
  #pragma unroll
  for (int i = 0; i < 8; i++) {
    float xn = (v[i] - mu) * rinv * nw[n + i] + nb[n + i];
    float y = xn * (1.0f + t[D + n + i]) + t[n + i];
    o[i] = f2bf(y);
  }
  *(uint4*)(out + (size_t)tok * D + n) = *(uint4*)o;
}

// ---------- GEMM: C(MxN,f32) = A(MxK,bf16) @ BT(NxK,bf16)^T + bias ----------
__global__ __launch_bounds__(256) void gemm_bf16(
    const us16* __restrict__ A, const us16* __restrict__ BT,
    const float* __restrict__ bias, float* __restrict__ C,
    int M, int N, int K) {
  __shared__ __align__(16) us16 As[64][40];
  __shared__ __align__(16) us16 Bs[64][40];
  int tid = threadIdx.x;
  int w = tid >> 6, l = tid & 63;
  int m0 = blockIdx.y << 6, n0 = blockIdx.x << 6;
  int lrow = tid >> 2, lk = (tid & 3) << 3;
  const us16* Ap = A + (size_t)(m0 + lrow) * K + lk;
  const us16* Bp = BT + (size_t)(n0 + lrow) * K + lk;
  int arow = (w << 4) + (l & 15);
  int koff = (l >> 4) << 3;
  int ncol = l & 15;
  f32x4 acc[4] = {};
  for (int k0 = 0; k0 < K; k0 += 32) {
    uint4 av = *(const uint4*)(Ap + k0);
    uint4 bv = *(const uint4*)(Bp + k0);
    __syncthreads();
    *(uint4*)&As[lrow][lk] = av;
    *(uint4*)&Bs[lrow][lk] = bv;
    __syncthreads();
    bf16x8 af = *(const bf16x8*)&As[arow][koff];
    bf16x8 b0 = *(const bf16x8*)&Bs[ncol][koff];
    bf16x8 b1 = *(const bf16x8*)&Bs[16 + ncol][koff];
    bf16x8 b2 = *(const bf16x8*)&Bs[32 + ncol][koff];
    bf16x8 b3 = *(const bf16x8*)&Bs[48 + ncol][koff];
    acc[0] = __builtin_amdgcn_mfma_f32_16x16x32_bf16(af, b0, acc[0], 0, 0, 0);
    acc[1] = __builtin_amdgcn_mfma_f32_16x16x32_bf16(af, b1, acc[1], 0, 0, 0);
    acc[2] = __builtin_amdgcn_mfma_f32_16x16x32_bf16(af, b2, acc[2], 0, 0, 0);
    acc[3] = __builtin_amdgcn_mfma_f32_16x16x32_bf16(af, b3, acc[3], 0, 0, 0);
  }
  int r0 = m0 + (w << 4) + ((l >> 4) << 2);
  #pragma unroll
  for (int nt = 0; nt < 4; nt++) {
    int col = n0 + nt * 16 + ncol;
    float bv = bias ? bias[col] : 0.0f;
    #pragma unroll
    for (int r = 0; r < 4; r++)
      C[(size_t)(r0 + r) * N + col] = acc[nt][r] + bv;
  }
}

// ---------- QK rmsnorm + rope + combine-scatter (mode 0=q,1=k,2=v) ----------
__global__ __launch_bounds__(256) void qkv_scatter(
    const float* __restrict__ in, const float* __restrict__ nw,
    const float* __restrict__ cosv, const float* __restrict__ sinv,
    us16* __restrict__ out, int mode, int is_ref) {
  __shared__ float red[4];
  int t = blockIdx.x, tid = threadIdx.x;
  const float* xr = in + (size_t)t * D;
  float v[8];
  float4 a = *(const float4*)(xr + tid * 8);
  float4 b = *(const float4*)(xr + tid * 8 + 4);
  v[0]=a.x; v[1]=a.y; v[2]=a.z; v[3]=a.w; v[4]=b.x; v[5]=b.y; v[6]=b.z; v[7]=b.w;
  int n = tid * 8;
  int head = n >> 7, d = n & 127;
  float o8[8];
  if (mode < 2) {
    float s = 0;
    #pragma unroll
    for (int i = 0; i < 8; i++) s += v[i] * v[i];
    float tot = blk_sum256(s, red, tid);
    float rinv = rsqrtf(tot * (1.0f / D) + 1e-6f);
    const float* cr = cosv + (size_t)t * HD;
    const float* sr = sinv + (size_t)t * HD;
    #pragma unroll
    for (int p = 0; p < 4; p++) {
      float x1 = v[2 * p] * rinv * nw[n + 2 * p];
      float x2 = v[2 * p + 1] * rinv * nw[n + 2 * p + 1];
      float ce = cr[d + 2 * p];
      float so = sr[d + 2 * p + 1];
      o8[2 * p]     = x1 * ce - x2 * so;
      o8[2 * p + 1] = x1 * so + x2 * ce;
    }
    if (mode == 0) {
      #pragma unroll
      for (int i = 0; i < 8; i++) o8[i] *= ATTN_SCALE;
    }
  } else {
    #pragma unroll
    for (int i = 0; i < 8; i++) o8[i] = v[i];
  }
  int f = t / 576, rem = t % 576;
  int row = rem / 24, col = rem - row * 24;
  int comb = row * 48 + col + (is_ref ? 24 : 0);
  size_t oidx = ((size_t)(f * NH + head) * CT + comb) * HD + d;
  us16 packed[8];
  #pragma unroll
  for (int i = 0; i < 8; i++) packed[i] = f2bf(o8[i]);
  *(uint4*)(out + oidx) = *(uint4*)packed;
}

// ---------- MFMA flash attention ----------
// grid: 64 fh * 18 q-tiles; block 256 (4 waves x 16 queries)
__global__ __launch_bounds__(256) void attn_mfma(
    const us16* __restrict__ qc, const us16* __restrict__ kc,
    const us16* __restrict__ vc, us16* __restrict__ ah, us16* __restrict__ ar) {
  __shared__ __align__(16) us16 Qs[64][136];     // stride 272B: frag-read 2-way banks
  __shared__ __align__(16) us16 Ks[64][136];
  __shared__ __align__(16) us16 Vts[128][72];    // transposed V: [d][key]
  __shared__ __align__(16) us16 Ps[4][16][72];   // per-wave P round-trip (C->A layout)
  int tid = threadIdx.x;
  int w = tid >> 6, l = tid & 63;
  int m = l & 15, quad = l >> 4;
  int bx = blockIdx.x;
  int fh = bx / 18, qt = bx % 18;
  size_t base = (size_t)fh * CT * HD;
  int qbase = qt * 64;

  // stage Q tile (64 x 128)
  {
    int row = tid >> 2, c0 = (tid & 3) * 32;
    const us16* src = qc + base + (size_t)(qbase + row) * HD + c0;
    #pragma unroll
    for (int j = 0; j < 4; j++)
      *(uint4*)&Qs[row][c0 + 8 * j] = *(const uint4*)(src + 8 * j);
  }
  __syncthreads();
  // hoist Q A-fragments (invariant over key chunks)
  bf16x8 qf[4];
  #pragma unroll
  for (int c = 0; c < 4; c++)
    qf[c] = *(const bf16x8*)&Qs[16 * w + m][32 * c + quad * 8];

  float mo[4] = {-1e30f, -1e30f, -1e30f, -1e30f};
  float li[4] = {0.f, 0.f, 0.f, 0.f};
  f32x4 o[8] = {};

  #pragma unroll 1
  for (int kb = 0; kb < CT; kb += 64) {
    __syncthreads();   // previous chunk's reads of Ks/Vts/Ps done
    // stage K chunk (row-major)
    {
      int row = tid >> 2, c0 = (tid & 3) * 32;
      const us16* src = kc + base + (size_t)(kb + row) * HD + c0;
      #pragma unroll
      for (int j = 0; j < 4; j++)
        *(uint4*)&Ks[row][c0 + 8 * j] = *(const uint4*)(src + 8 * j);
    }
    // stage V chunk transposed: lane = key so LDS writes pair into dwords (conflict-free)
    {
      int key = tid & 63, d0 = (tid >> 6) * 32;
      const us16* src = vc + base + (size_t)(kb + key) * HD + d0;
      #pragma unroll
      for (int j = 0; j < 4; j++) {
        uint4 vv = *(const uint4*)(src + 8 * j);
        us16 tmp[8];
        *(uint4*)tmp = vv;
        #pragma unroll
        for (int i = 0; i < 8; i++) Vts[d0 + 8 * j + i][key] = tmp[i];
      }
    }
    __syncthreads();
    // S = Q K^T : 16 queries x 64 keys per wave
    f32x4 s[4] = {};
    #pragma unroll
    for (int kt = 0; kt < 4; kt++) {
      #pragma unroll
      for (int c = 0; c < 4; c++) {
        bf16x8 kf = *(const bf16x8*)&Ks[kt * 16 + m][32 * c + quad * 8];
        s[kt] = __builtin_amdgcn_mfma_f32_16x16x32_bf16(qf[c], kf, s[kt], 0, 0, 0);
      }
    }
    // online softmax: row r lives at quad*4+r, cols spread over 16 lanes x 4 kt
    float al[4];
    #pragma unroll
    for (int r = 0; r < 4; r++) {
      float v = fmaxf(fmaxf(s[0][r], s[1][r]), fmaxf(s[2][r], s[3][r]));
      #pragma unroll
      for (int off = 8; off; off >>= 1) v = fmaxf(v, __shfl_xor(v, off));
      float mn = fmaxf(mo[r], v);
      al[r] = __expf(mo[r] - mn);
      mo[r] = mn;
      float ps = 0.f;
      #pragma unroll
      for (int kt = 0; kt < 4; kt++) {
        float p = __expf(s[kt][r] - mn);
        s[kt][r] = p;
        ps += p;
      }
      #pragma unroll
      for (int off = 8; off; off >>= 1) ps += __shfl_xor(ps, off);
      li[r] = li[r] * al[r] + ps;
    }
    // P: C-layout -> LDS (A-layout rows)
    #pragma unroll
    for (int kt = 0; kt < 4; kt++)
      #pragma unroll
      for (int r = 0; r < 4; r++)
        Ps[w][quad * 4 + r][kt * 16 + m] = f2bf(s[kt][r]);
    // rescale O accumulators (row alignment: quad*4+reg in both layouts)
    #pragma unroll
    for (int dt = 0; dt < 8; dt++)
      #pragma unroll
      for (int r = 0; r < 4; r++)
        o[dt][r] *= al[r];
    // RACE FIX (R2 post-mortem): the Ps round-trip is cross-LANE data exchange
    // (lane reads bf16x8 vectors written as us16 scalars by other lanes).
    // TBAA treats us16 stores vs __bf16 loads as no-alias, so without a
    // barrier the compiler need not order/wait them -> nondeterministic
    // divergence under graph replay. s_barrier's unconditional
    // s_waitcnt lgkmcnt(0) ignores aliasing.
    __syncthreads();
    // O += P V  (A = P from Ps, B = V^T from Vts)
    #pragma unroll
    for (int c = 0; c < 2; c++) {
      bf16x8 pf = *(const bf16x8*)&Ps[w][m][32 * c + quad * 8];
      #pragma unroll
      for (int dt = 0; dt < 8; dt++) {
        bf16x8 vf = *(const bf16x8*)&Vts[dt * 16 + m][32 * c + quad * 8];
        o[dt] = __builtin_amdgcn_mfma_f32_16x16x32_bf16(pf, vf, o[dt], 0, 0, 0);
      }
    }
  }
  // epilogue: normalize, un-combine, scatter to ah/ar token-major
  int f = fh >> 4, h = fh & 15;
  #pragma unroll
  for (int r = 0; r < 4; r++) {
    float rl = 1.0f / li[r];
    int q = qbase + 16 * w + quad * 4 + r;
    int row = q / 48, cc = q - row * 48;
    int isr = cc >= 24;
    int tok = f * 576 + row * 24 + (isr ? cc - 24 : cc);
    us16* dstp = (isr ? ar : ah) + (size_t)tok * D + h * HD;
    #pragma unroll
    for (int dt = 0; dt < 8; dt++)
      dstp[dt * 16 + m] = f2bf(o[dt][r] * rl);
  }
}

// ---------- out = x + gate[col] * attn ----------
__global__ __launch_bounds__(256) void residual_gate(
    const float* __restrict__ x, const float* __restrict__ attn,
    const float* __restrict__ gate, float* __restrict__ out) {
  size_t i = ((size_t)blockIdx.x * 256 + threadIdx.x) * 4;
  float4 xv = *(const float4*)(x + i);
  float4 av = *(const float4*)(attn + i);
  int n = (int)(i & (D - 1));
  float4 g = *(const float4*)(gate + n);
  float4 o;
  o.x = xv.x + g.x * av.x;
  o.y = xv.y + g.y * av.y;
  o.z = xv.z + g.z * av.z;
  o.w = xv.w + g.w * av.w;
  *(float4*)(out + i) = o;
}

// ---------- gelu(tanh) fp32 -> bf16 ----------
__device__ __forceinline__ float gelu_tanh(float x) {
  float y = 0.7978845608028654f * (x + 0.044715f * x * x * x);
  float e = __expf(2.0f * y);
  float t = 1.0f - 2.0f / (e + 1.0f);
  return 0.5f * x * (1.0f + t);
}
__global__ __launch_bounds__(256) void gelu_cvt(
    const float* __restrict__ in, us16* __restrict__ out, int n4) {
  int i = blockIdx.x * 256 + threadIdx.x;
  if (i >= n4) return;
  float4 v = *(const float4*)(in + (size_t)i * 4);
  us16 o[4];
  o[0] = f2bf(gelu_tanh(v.x));
  o[1] = f2bf(gelu_tanh(v.y));
  o[2] = f2bf(gelu_tanh(v.z));
  o[3] = f2bf(gelu_tanh(v.w));
  *(uint2*)(out + (size_t)i * 4) = *(uint2*)o;
}

// ---------- workspace layout (bytes) ----------
constexpr size_t O_WQ   = 0;
constexpr size_t O_WK   = 8388608;
constexpr size_t O_WV   = 16777216;
constexpr size_t O_WO   = 25165824;
constexpr size_t O_NH   = 33603584;   // bf16 S*D
constexpr size_t O_NR   = 43040768;
constexpr size_t O_RAW  = 52477952;   // 6 x fp32 S*D
constexpr size_t RAWSZ  = 18874368;
constexpr size_t O_QC   = 165724160;  // bf16 combined
constexpr size_t O_KC   = 184598528;
constexpr size_t O_VC   = 203472896;
constexpr size_t O_T1   = 222347264;  // fp32 6144
constexpr size_t O_T2   = 222371840;
constexpr size_t O_AH    = O_RAW;                 // bf16 S*D
constexpr size_t O_AR    = O_RAW + 9437184;       // bf16 S*D
constexpr size_t O_ATTNH = O_RAW + RAWSZ;         // fp32 S*D
constexpr size_t O_ATTNR = O_RAW + 2 * RAWSZ;     // fp32 S*D
constexpr size_t O_W1T  = 0;          // bf16 FFN*D transposed
constexpr size_t O_W2T  = 33554432;   // bf16 D*FFN transposed
constexpr size_t O_N2H  = 67108864;   // bf16 S*D
constexpr size_t O_N2R  = 76546048;
constexpr size_t O_MID  = 85983232;   // fp32 S*FFN
constexpr size_t O_MIDB = 161480704;  // bf16 S*FFN
constexpr size_t O_FOUT = 199229440;  // fp32 S*D

extern "C" void kernel_launch(void* const* d_in, const int* in_sizes, int n_in,
                              void* d_out, int out_size, void* d_ws, size_t ws_size,
                              hipStream_t stream) {
  (void)in_sizes; (void)n_in; (void)out_size; (void)ws_size;
  const float* hidden = (const float*)d_in[0];
  const float* refs   = (const float*)d_in[1];
  const float* temb   = (const float*)d_in[2];
  const float* cos_h  = (const float*)d_in[3];
  const float* sin_h  = (const float*)d_in[4];
  const float* cos_r  = (const float*)d_in[5];
  const float* sin_r  = (const float*)d_in[6];
  const float* ln1_lw = (const float*)d_in[7];
  const float* ln1_lb = (const float*)d_in[8];
  const float* ln1_nw = (const float*)d_in[9];
  const float* ln1_nb = (const float*)d_in[10];
  const float* ln2_lw = (const float*)d_in[11];
  const float* ln2_lb = (const float*)d_in[12];
  const float* ln2_nw = (const float*)d_in[13];
  const float* ln2_nb = (const float*)d_in[14];
  const float* wq = (const float*)d_in[15];
  const float* bq = (const float*)d_in[16];
  const float* wk = (const float*)d_in[17];
  const float* bk = (const float*)d_in[18];
  const float* wv = (const float*)d_in[19];
  const float* bv = (const float*)d_in[20];
  const float* nq_w = (const float*)d_in[21];
  const float* nk_w = (const float*)d_in[22];
  const float* wo = (const float*)d_in[23];
  const float* bo = (const float*)d_in[24];
  const float* ffn_w1 = (const float*)d_in[25];
  const float* ffn_b1 = (const float*)d_in[26];
  const float* ffn_w2 = (const float*)d_in[27];
  const float* ffn_b2 = (const float*)d_in[28];

  char* ws = (char*)d_ws;
  us16* p_wq = (us16*)(ws + O_WQ);
  us16* p_wk = (us16*)(ws + O_WK);
  us16* p_wv = (us16*)(ws + O_WV);
  us16* p_wo = (us16*)(ws + O_WO);
  us16* p_nh = (us16*)(ws + O_NH);
  us16* p_nr = (us16*)(ws + O_NR);
  float* p_raw[6];
  for (int i = 0; i < 6; i++) p_raw[i] = (float*)(ws + O_RAW + (size_t)i * RAWSZ);
  us16* p_qc = (us16*)(ws + O_QC);
  us16* p_kc = (us16*)(ws + O_KC);
  us16* p_vc = (us16*)(ws + O_VC);
  float* p_t1 = (float*)(ws + O_T1);
  float* p_t2 = (float*)(ws + O_T2);
  us16* p_ah = (us16*)(ws + O_AH);
  us16* p_ar = (us16*)(ws + O_AR);
  float* p_attnh = (float*)(ws + O_ATTNH);
  float* p_attnr = (float*)(ws + O_ATTNR);
  us16* p_w1t = (us16*)(ws + O_W1T);
  us16* p_w2t = (us16*)(ws + O_W2T);
  us16* p_n2h = (us16*)(ws + O_N2H);
  us16* p_n2r = (us16*)(ws + O_N2R);
  float* p_mid  = (float*)(ws + O_MID);
  us16*  p_midb = (us16*)(ws + O_MIDB);
  float* p_fout = (float*)(ws + O_FOUT);
  float* outh = (float*)d_out;
  float* outr = (float*)d_out + (size_t)S * D;

  dim3 tb(32, 8);
  transpose_cvt<<<dim3(64, 64), tb, 0, stream>>>(wq, p_wq, D, D);
  transpose_cvt<<<dim3(64, 64), tb, 0, stream>>>(wk, p_wk, D, D);
  transpose_cvt<<<dim3(64, 64), tb, 0, stream>>>(wv, p_wv, D, D);
  transpose_cvt<<<dim3(64, 64), tb, 0, stream>>>(wo, p_wo, D, D);
  temb_mod<<<48, 256, 0, stream>>>(temb, ln1_lw, ln1_lb, ln2_lw, ln2_lb, p_t1, p_t2);
  ln_mod<<<S, 256, 0, stream>>>(hidden, p_t1, ln1_nw, ln1_nb, p_nh);
  ln_mod<<<S, 256, 0, stream>>>(refs,   p_t1, ln1_nw, ln1_nb, p_nr);
  gemm_bf16<<<dim3(32, 36), 256, 0, stream>>>(p_nh, p_wq, bq, p_raw[0], S, D, D);
  gemm_bf16<<<dim3(32, 36), 256, 0, stream>>>(p_nh, p_wk, bk, p_raw[1], S, D, D);
  gemm_bf16<<<dim3(32, 36), 256, 0, stream>>>(p_nh, p_wv, bv, p_raw[2], S, D, D);
  gemm_bf16<<<dim3(32, 36), 256, 0, stream>>>(p_nr, p_wq, bq, p_raw[3], S, D, D);
  gemm_bf16<<<dim3(32, 36), 256, 0, stream>>>(p_nr, p_wk, bk, p_raw[4], S, D, D);
  gemm_bf16<<<dim3(32, 36), 256, 0, stream>>>(p_nr, p_wv, bv, p_raw[5], S, D, D);
  qkv_scatter<<<S, 256, 0, stream>>>(p_raw[0], nq_w, cos_h, sin_h, p_qc, 0, 0);
  qkv_scatter<<<S, 256, 0, stream>>>(p_raw[1], nk_w, cos_h, sin_h, p_kc, 1, 0);
  qkv_scatter<<<S, 256, 0, stream>>>(p_raw[2], nq_w, cos_h, sin_h, p_vc, 2, 0);
  qkv_scatter<<<S, 256, 0, stream>>>(p_raw[3], nq_w, cos_r, sin_r, p_qc, 0, 1);
  qkv_scatter<<<S, 256, 0, stream>>>(p_raw[4], nk_w, cos_r, sin_r, p_kc, 1, 1);
  qkv_scatter<<<S, 256, 0, stream>>>(p_raw[5], nq_w, cos_r, sin_r, p_vc, 2, 1);
  attn_mfma<<<F4 * NH * 18, 256, 0, stream>>>(p_qc, p_kc, p_vc, p_ah, p_ar);
  gemm_bf16<<<dim3(32, 36), 256, 0, stream>>>(p_ah, p_wo, bo, p_attnh, S, D, D);
  gemm_bf16<<<dim3(32, 36), 256, 0, stream>>>(p_ar, p_wo, bo, p_attnr, S, D, D);
  residual_gate<<<4608, 256, 0, stream>>>(hidden, p_attnh, p_t1 + 2 * D, outh);
  residual_gate<<<4608, 256, 0, stream>>>(refs,   p_attnr, p_t1 + 2 * D, outr);
  transpose_cvt<<<dim3(256, 64), tb, 0, stream>>>(ffn_w1, p_w1t, D, FFN);
  transpose_cvt<<<dim3(64, 256), tb, 0, stream>>>(ffn_w2, p_w2t, FFN, D);
  ln_mod<<<S, 256, 0, stream>>>(outh, p_t2, ln2_nw, ln2_nb, p_n2h);
  ln_mod<<<S, 256, 0, stream>>>(outr, p_t2, ln2_nw, ln2_nb, p_n2r);
  gemm_bf16<<<dim3(128, 36), 256, 0, stream>>>(p_n2h, p_w1t, ffn_b1, p_mid, S, FFN, D);
  gelu_cvt<<<18432, 256, 0, stream>>>(p_mid, p_midb, (S * FFN) / 4);
  gemm_bf16<<<dim3(32, 36), 256, 0, stream>>>(p_midb, p_w2t, ffn_b2, p_fout, S, D, FFN);
  residual_gate<<<4608, 256, 0, stream>>>(outh, p_fout, p_t2 + 2 * D, outh);
  gemm_bf16<<<dim3(128, 36), 256, 0, stream>>>(p_n2r, p_w1t, ffn_b1, p_mid, S, FFN, D);
  gelu_cvt<<<18432, 256, 0, stream>>>(p_mid, p_midb, (S * FFN) / 4);
  gemm_bf16<<<dim3(32, 36), 256, 0, stream>>>(p_midb, p_w2t, ffn_b2, p_fout, S, D, FFN);
  residual_gate<<<4608, 256, 0, stream>>>(outr, p_fout, p_t2 + 2 * D, outr);
}